// Round 4
// baseline (3232.064 us; speedup 1.0000x reference)
//
#include <hip/hip_runtime.h>
#include <hip/hip_bf16.h>

// GenericLSTM: B=64 T=2048 I=128 H=256, fp32 in/out.
// Plan: (1) pack W_h -> int8 per-column-scaled, (2) pack W_x -> bf16 in MFMA
// fragment order, (3) one MFMA GEMM computes g_x = inputs@W_x for all t (f16),
// (4) persistent recurrent kernel: 1 WG per sample, 256 threads, each thread
// owns ALL 4 gates of one H-column: no gate exchange, one barrier per step,
// 1 wave/SIMD, W_h register-resident (arch VGPR + AGPR), v_dot4 inner product.

#define B_ 64
#define T_ 2048
#define I_ 128
#define H_ 256
#define NC 1024  // 4 gates * H columns

typedef __attribute__((ext_vector_type(8))) short bf16x8;
typedef __attribute__((ext_vector_type(4))) float f32x4;

static __device__ __forceinline__ unsigned short f2bf(float f) {
    unsigned u = __builtin_bit_cast(unsigned, f);
    u = (u + 0x7FFFu + ((u >> 16) & 1u)) >> 16;
    return (unsigned short)u;
}

static __device__ __forceinline__ int dot4(unsigned a, unsigned b, int c) {
#if __has_builtin(__builtin_amdgcn_sdot4)
    return __builtin_amdgcn_sdot4((int)a, (int)b, c, false);
#else
    int r = c;
    r += (int)(signed char)(a) * (int)(signed char)(b);
    r += (int)(signed char)(a >> 8) * (int)(signed char)(b >> 8);
    r += (int)(signed char)(a >> 16) * (int)(signed char)(b >> 16);
    r += (int)(signed char)(a >> 24) * (int)(signed char)(b >> 24);
    return r;
#endif
}

static __device__ __forceinline__ float fastrcp(float x) {
    return __builtin_amdgcn_rcpf(x);
}

// ---------------- P1: W_h [4,256,256] f32 -> int8 packed [col][k/4 dwords] +
// per-col scale (scale already includes the 1/127 h dequant factor).
__global__ void pack_wh(const float* __restrict__ Wh, unsigned* __restrict__ wq,
                        float* __restrict__ sws) {
    int col = blockIdx.x;              // 0..1023 = g*256 + j
    int g = col >> 8, j = col & 255;
    int lane = threadIdx.x;            // 0..63, covers k = 4*lane..4*lane+3
    float v[4];
    float m = 0.f;
#pragma unroll
    for (int u = 0; u < 4; ++u) {
        int k = lane * 4 + u;
        v[u] = Wh[(g * H_ + k) * H_ + j];
        m = fmaxf(m, fabsf(v[u]));
    }
#pragma unroll
    for (int off = 32; off; off >>= 1) m = fmaxf(m, __shfl_xor(m, off));
    float mm = (m > 0.f) ? m : 1.f;
    float inv = 127.f / mm;
    unsigned pack = 0;
#pragma unroll
    for (int u = 0; u < 4; ++u) {
        int q = (int)rintf(v[u] * inv);
        q = max(-127, min(127, q));
        pack |= ((unsigned)(q & 255)) << (8 * u);
    }
    wq[col * 64 + lane] = pack;
    if (lane == 0) sws[col] = mm / (127.f * 127.f);  // S_col/127
}

// ---------------- P2: W_x [4,128,256] f32 -> bf16 in MFMA-fragment order:
// Bfrag[((ki*4+q)*1024 + col)*8 + j] = W_x[g][k][h], k = (ki)*32 + q*8 + j.
__global__ void pack_wx(const float* __restrict__ Wx,
                        unsigned short* __restrict__ bxp) {
    int f = blockIdx.x * blockDim.x + threadIdx.x;  // 0..131071
    int j = f & 7;
    int col = (f >> 3) & 1023;
    int c16 = f >> 13;  // 0..15
    int k = (c16 >> 2) * 32 + (c16 & 3) * 8 + j;
    int g = col >> 8, h = col & 255;
    bxp[f] = f2bf(Wx[(g * I_ + k) * H_ + h]);
}

// ---------------- GEMM: g_x[row][col] = sum_k inputs[row][k] * W_x[k][col]
// rows = b*T+t (131072), cols = 1024, K = 128 (single shot, no k-loop).
// Output stored as f16.
__global__ __launch_bounds__(256) void gemm_gx(
    const float* __restrict__ A, const unsigned short* __restrict__ Bp,
    unsigned short* __restrict__ Cg) {
    __shared__ uint4 sm[4096];  // 64 KB: As = [0..2047], Bs = [2048..4095]
    int tid = threadIdx.x;
    int mt = blockIdx.x, nt = blockIdx.y;

    // Stage A tile (128 rows x 128 k), f32 -> bf16, fragment-order layout:
    // As[(c16*128+m)] is a 16B vector holding k-j 0..7 for that (c16,m).
    const float* Ab = A + (size_t)mt * 128 * I_;
    unsigned* dstA = (unsigned*)sm;
#pragma unroll
    for (int it = 0; it < 16; ++it) {
        int flat = it * 1024 + tid * 4;
        float4 a4 = *(const float4*)(Ab + flat);
        int m = flat >> 7, k0 = flat & 127;
        int c16 = k0 >> 3, j0 = k0 & 7;  // j0 in {0,4}
        unsigned lo = (unsigned)f2bf(a4.x) | ((unsigned)f2bf(a4.y) << 16);
        unsigned hi = (unsigned)f2bf(a4.z) | ((unsigned)f2bf(a4.w) << 16);
        int didx = ((c16 * 128 + m) * 16 + j0 * 2) >> 2;
        dstA[didx] = lo;
        dstA[didx + 1] = hi;
    }
    // Stage B tile (prepacked fragment order): contiguous 16B per (c16,col).
    const uint4* Bq = (const uint4*)Bp;
#pragma unroll
    for (int it = 0; it < 8; ++it) {
        int chunk = it * 2 + (tid >> 7);
        int inner = tid & 127;
        sm[2048 + chunk * 128 + inner] = Bq[chunk * 1024 + nt * 128 + inner];
    }
    __syncthreads();

    int wid = tid >> 6, lane = tid & 63;
    int r = lane & 15, q = lane >> 4;
    int mw = (wid & 1) * 64, nw = (wid >> 1) * 64;
    f32x4 acc[4][4] = {};
#pragma unroll
    for (int ki = 0; ki < 4; ++ki) {
        bf16x8 af[4], bfr[4];
#pragma unroll
        for (int x = 0; x < 4; ++x) {
            af[x] = __builtin_bit_cast(bf16x8,
                                       sm[(ki * 4 + q) * 128 + mw + x * 16 + r]);
            bfr[x] = __builtin_bit_cast(
                bf16x8, sm[2048 + (ki * 4 + q) * 128 + nw + x * 16 + r]);
        }
#pragma unroll
        for (int x = 0; x < 4; ++x)
#pragma unroll
            for (int y = 0; y < 4; ++y)
                acc[x][y] = __builtin_amdgcn_mfma_f32_16x16x32_bf16(
                    af[x], bfr[y], acc[x][y], 0, 0, 0);
    }
    __syncthreads();

    // C frags (col=lane&15, row=q*4+reg) -> LDS f16 tile, then coalesced store.
    _Float16* ct = (_Float16*)sm;
#pragma unroll
    for (int x = 0; x < 4; ++x)
#pragma unroll
        for (int y = 0; y < 4; ++y)
#pragma unroll
            for (int g2 = 0; g2 < 4; ++g2) {
                int row = mw + x * 16 + q * 4 + g2;
                int colc = nw + y * 16 + r;
                ct[row * 128 + colc] = (_Float16)acc[x][y][g2];
            }
    __syncthreads();
    int m = tid >> 1, half = tid & 1;
    const uint4* src = (const uint4*)sm;
    uint4* dstg =
        (uint4*)(Cg + ((size_t)(mt * 128 + m) * NC + nt * 128 + half * 64));
#pragma unroll
    for (int i = 0; i < 8; ++i) dstg[i] = src[m * 16 + half * 8 + i];
}

// ---------------- Recurrent kernel: 64 WGs (1/sample) x 256 threads.
// Thread j owns all 4 gate-cols {j, 256+j, 512+j, 768+j} and the (c,h) state
// for H-column j. No gate exchange, ONE barrier per step, 1 wave/SIMD
// (launch_bounds(256,1) -> big register budget; W_h 256 dwords/thread
// register-resident). h carried as int8 (scale 1/127), double buffered in LDS;
// broadcast via same-address ds_read_b128 (conflict-free).
__global__ __launch_bounds__(256, 1) void lstm_rec(
    const unsigned short* __restrict__ gx, const uint4* __restrict__ wq4,
    const float* __restrict__ sws, const float* __restrict__ bias,
    float* __restrict__ out) {
    int b = blockIdx.x, j = threadIdx.x;  // j = H column

    // 4 gates x 16 uint4 = 256 dwords of int8 weights, register-resident.
    uint4 w0[16], w1[16], w2[16], w3[16];
#pragma unroll
    for (int i = 0; i < 16; ++i) {
        w0[i] = wq4[(0 * H_ + j) * 16 + i];
        w1[i] = wq4[(1 * H_ + j) * 16 + i];
        w2[i] = wq4[(2 * H_ + j) * 16 + i];
        w3[i] = wq4[(3 * H_ + j) * 16 + i];
    }
    float s0 = sws[0 * H_ + j], s1 = sws[1 * H_ + j];
    float s2 = sws[2 * H_ + j], s3 = sws[3 * H_ + j];
    float b0 = bias[0 * H_ + j], b1 = bias[1 * H_ + j];
    float b2 = bias[2 * H_ + j], b3 = bias[3 * H_ + j];

    __shared__ uint4 hq[2][16];  // 256 int8 h values, double buffered
    if (j < 16) hq[0][j] = (uint4){0u, 0u, 0u, 0u};
    __syncthreads();

    float c = 0.f;
    const _Float16* gxh = (const _Float16*)gx;
    size_t rowbase = (size_t)b * T_;
    float gv0 = (float)gxh[rowbase * NC + 0 * H_ + j];
    float gv1 = (float)gxh[rowbase * NC + 1 * H_ + j];
    float gv2 = (float)gxh[rowbase * NC + 2 * H_ + j];
    float gv3 = (float)gxh[rowbase * NC + 3 * H_ + j];

    for (int t = 0; t < T_; ++t) {
        size_t row = rowbase + t;
        // prefetch next step's g_x (clamped at the last step; value unused)
        size_t prow = rowbase + ((t < T_ - 1) ? (t + 1) : t);
        float nv0 = (float)gxh[prow * NC + 0 * H_ + j];
        float nv1 = (float)gxh[prow * NC + 1 * H_ + j];
        float nv2 = (float)gxh[prow * NC + 2 * H_ + j];
        float nv3 = (float)gxh[prow * NC + 3 * H_ + j];

        // broadcast h (all lanes same address -> LDS broadcast, no conflict)
        const uint4* hb = hq[t & 1];
        // 8 accumulator chains (2 per gate) for ILP
        int a0 = 0, a1 = 0, a2 = 0, a3 = 0;
        int e0 = 0, e1 = 0, e2 = 0, e3 = 0;
#pragma unroll
        for (int i = 0; i < 16; i += 2) {
            uint4 h0 = hb[i], h1 = hb[i + 1];
            a0 = dot4(w0[i].x, h0.x, a0); a0 = dot4(w0[i].y, h0.y, a0);
            a0 = dot4(w0[i].z, h0.z, a0); a0 = dot4(w0[i].w, h0.w, a0);
            a1 = dot4(w1[i].x, h0.x, a1); a1 = dot4(w1[i].y, h0.y, a1);
            a1 = dot4(w1[i].z, h0.z, a1); a1 = dot4(w1[i].w, h0.w, a1);
            a2 = dot4(w2[i].x, h0.x, a2); a2 = dot4(w2[i].y, h0.y, a2);
            a2 = dot4(w2[i].z, h0.z, a2); a2 = dot4(w2[i].w, h0.w, a2);
            a3 = dot4(w3[i].x, h0.x, a3); a3 = dot4(w3[i].y, h0.y, a3);
            a3 = dot4(w3[i].z, h0.z, a3); a3 = dot4(w3[i].w, h0.w, a3);
            e0 = dot4(w0[i + 1].x, h1.x, e0); e0 = dot4(w0[i + 1].y, h1.y, e0);
            e0 = dot4(w0[i + 1].z, h1.z, e0); e0 = dot4(w0[i + 1].w, h1.w, e0);
            e1 = dot4(w1[i + 1].x, h1.x, e1); e1 = dot4(w1[i + 1].y, h1.y, e1);
            e1 = dot4(w1[i + 1].z, h1.z, e1); e1 = dot4(w1[i + 1].w, h1.w, e1);
            e2 = dot4(w2[i + 1].x, h1.x, e2); e2 = dot4(w2[i + 1].y, h1.y, e2);
            e2 = dot4(w2[i + 1].z, h1.z, e2); e2 = dot4(w2[i + 1].w, h1.w, e2);
            e3 = dot4(w3[i + 1].x, h1.x, e3); e3 = dot4(w3[i + 1].y, h1.y, e3);
            e3 = dot4(w3[i + 1].z, h1.z, e3); e3 = dot4(w3[i + 1].w, h1.w, e3);
        }
        float g0 = (float)(a0 + e0) * s0 + gv0 + b0;  // i gate pre-act
        float g1 = (float)(a1 + e1) * s1 + gv1 + b1;  // f gate
        float g2 = (float)(a2 + e2) * s2 + gv2 + b2;  // g (context) gate
        float g3 = (float)(a3 + e3) * s3 + gv3 + b3;  // o gate

        float ig = fastrcp(1.f + __expf(-g0));
        float fg = fastrcp(1.f + __expf(-g1));
        float eg = __expf(-2.f * g2);
        float gg = 2.f * fastrcp(1.f + eg) - 1.f;     // tanh, inf-safe
        float og = fastrcp(1.f + __expf(-g3));

        c = fg * c + ig * gg;
        float ec = __expf(-2.f * c);
        float th = 2.f * fastrcp(1.f + ec) - 1.f;     // tanh(c)
        float h = og * th;
        out[row * H_ + j] = h;
        int qv = (int)rintf(h * 127.f);
        ((signed char*)hq[(t + 1) & 1])[j] = (signed char)qv;
        __syncthreads();  // step t writes (other buffer) vs step t+1 reads

        gv0 = nv0; gv1 = nv1; gv2 = nv2; gv3 = nv3;
    }
}

extern "C" void kernel_launch(void* const* d_in, const int* in_sizes, int n_in,
                              void* d_out, int out_size, void* d_ws,
                              size_t ws_size, hipStream_t stream) {
    const float* inputs = (const float*)d_in[0];
    const float* Wx = (const float*)d_in[1];
    const float* Wh = (const float*)d_in[2];
    const float* bias = (const float*)d_in[3];
    float* out = (float*)d_out;

    char* ws = (char*)d_ws;
    unsigned short* gxbuf = (unsigned short*)ws;   // 131072*1024 f16 = 256 MiB
    size_t off = (size_t)B_ * T_ * NC * 2;
    unsigned* wq = (unsigned*)(ws + off);          // 256 KiB int8 W_h
    off += (size_t)NC * 64 * 4;
    float* sws = (float*)(ws + off);               // 4 KiB scales
    off += (size_t)NC * 4;
    unsigned short* bxp = (unsigned short*)(ws + off);  // 256 KiB bf16 W_x
    off += (size_t)I_ * NC * 2;

    pack_wh<<<NC, 64, 0, stream>>>(Wh, wq, sws);
    pack_wx<<<(I_ * NC) / 256, 256, 0, stream>>>(Wx, bxp);
    gemm_gx<<<dim3((B_ * T_) / 128, NC / 128), 256, 0, stream>>>(inputs, bxp,
                                                                 gxbuf);
    lstm_rec<<<B_, 256, 0, stream>>>(gxbuf, (const uint4*)wq, sws, bias, out);
}

// Round 5
// 2291.865 us; speedup vs baseline: 1.4102x; 1.4102x over previous
//
#include <hip/hip_runtime.h>
#include <hip/hip_bf16.h>

// GenericLSTM: B=64 T=2048 I=128 H=256, fp32 in/out.
// Plan: (1) pack W_h -> int8 per-column-scaled, (2) pack W_x -> bf16 in MFMA
// fragment order, (3) one MFMA GEMM computes g_x = inputs@W_x for all t (f16),
// (4) persistent recurrent kernel: 1 WG/sample, 1024 threads (16 waves,
// 4/SIMD for latency hiding). Lane = gate*16 + (col%16): all 4 gates of a
// column live in ONE wave -> gate exchange via __shfl (no barrier), ONE
// __syncthreads per step (h double-buffer). W_h int8 in VGPRs, v_dot4 dots.

#define B_ 64
#define T_ 2048
#define I_ 128
#define H_ 256
#define NC 1024  // 4 gates * H columns

typedef __attribute__((ext_vector_type(8))) short bf16x8;
typedef __attribute__((ext_vector_type(4))) float f32x4;

static __device__ __forceinline__ unsigned short f2bf(float f) {
    unsigned u = __builtin_bit_cast(unsigned, f);
    u = (u + 0x7FFFu + ((u >> 16) & 1u)) >> 16;
    return (unsigned short)u;
}

static __device__ __forceinline__ int dot4(unsigned a, unsigned b, int c) {
#if __has_builtin(__builtin_amdgcn_sdot4)
    return __builtin_amdgcn_sdot4((int)a, (int)b, c, false);
#else
    int r = c;
    r += (int)(signed char)(a) * (int)(signed char)(b);
    r += (int)(signed char)(a >> 8) * (int)(signed char)(b >> 8);
    r += (int)(signed char)(a >> 16) * (int)(signed char)(b >> 16);
    r += (int)(signed char)(a >> 24) * (int)(signed char)(b >> 24);
    return r;
#endif
}

static __device__ __forceinline__ float fastrcp(float x) {
    return __builtin_amdgcn_rcpf(x);
}

// ---------------- P1: W_h [4,256,256] f32 -> int8 packed [col][k/4 dwords] +
// per-col scale (scale already includes the 1/127 h dequant factor).
__global__ void pack_wh(const float* __restrict__ Wh, unsigned* __restrict__ wq,
                        float* __restrict__ sws) {
    int col = blockIdx.x;              // 0..1023 = g*256 + j
    int g = col >> 8, j = col & 255;
    int lane = threadIdx.x;            // 0..63, covers k = 4*lane..4*lane+3
    float v[4];
    float m = 0.f;
#pragma unroll
    for (int u = 0; u < 4; ++u) {
        int k = lane * 4 + u;
        v[u] = Wh[(g * H_ + k) * H_ + j];
        m = fmaxf(m, fabsf(v[u]));
    }
#pragma unroll
    for (int off = 32; off; off >>= 1) m = fmaxf(m, __shfl_xor(m, off));
    float mm = (m > 0.f) ? m : 1.f;
    float inv = 127.f / mm;
    unsigned pack = 0;
#pragma unroll
    for (int u = 0; u < 4; ++u) {
        int q = (int)rintf(v[u] * inv);
        q = max(-127, min(127, q));
        pack |= ((unsigned)(q & 255)) << (8 * u);
    }
    wq[col * 64 + lane] = pack;
    if (lane == 0) sws[col] = mm / (127.f * 127.f);  // S_col/127
}

// ---------------- P2: W_x [4,128,256] f32 -> bf16 in MFMA-fragment order:
// Bfrag[((ki*4+q)*1024 + col)*8 + j] = W_x[g][k][h], k = (ki)*32 + q*8 + j.
__global__ void pack_wx(const float* __restrict__ Wx,
                        unsigned short* __restrict__ bxp) {
    int f = blockIdx.x * blockDim.x + threadIdx.x;  // 0..131071
    int j = f & 7;
    int col = (f >> 3) & 1023;
    int c16 = f >> 13;  // 0..15
    int k = (c16 >> 2) * 32 + (c16 & 3) * 8 + j;
    int g = col >> 8, h = col & 255;
    bxp[f] = f2bf(Wx[(g * I_ + k) * H_ + h]);
}

// ---------------- GEMM: g_x[row][col] = sum_k inputs[row][k] * W_x[k][col]
// rows = b*T+t (131072), cols = 1024, K = 128 (single shot, no k-loop).
// Output stored as f16.
__global__ __launch_bounds__(256) void gemm_gx(
    const float* __restrict__ A, const unsigned short* __restrict__ Bp,
    unsigned short* __restrict__ Cg) {
    __shared__ uint4 sm[4096];  // 64 KB: As = [0..2047], Bs = [2048..4095]
    int tid = threadIdx.x;
    int mt = blockIdx.x, nt = blockIdx.y;

    // Stage A tile (128 rows x 128 k), f32 -> bf16, fragment-order layout:
    // As[(c16*128+m)] is a 16B vector holding k-j 0..7 for that (c16,m).
    const float* Ab = A + (size_t)mt * 128 * I_;
    unsigned* dstA = (unsigned*)sm;
#pragma unroll
    for (int it = 0; it < 16; ++it) {
        int flat = it * 1024 + tid * 4;
        float4 a4 = *(const float4*)(Ab + flat);
        int m = flat >> 7, k0 = flat & 127;
        int c16 = k0 >> 3, j0 = k0 & 7;  // j0 in {0,4}
        unsigned lo = (unsigned)f2bf(a4.x) | ((unsigned)f2bf(a4.y) << 16);
        unsigned hi = (unsigned)f2bf(a4.z) | ((unsigned)f2bf(a4.w) << 16);
        int didx = ((c16 * 128 + m) * 16 + j0 * 2) >> 2;
        dstA[didx] = lo;
        dstA[didx + 1] = hi;
    }
    // Stage B tile (prepacked fragment order): contiguous 16B per (c16,col).
    const uint4* Bq = (const uint4*)Bp;
#pragma unroll
    for (int it = 0; it < 8; ++it) {
        int chunk = it * 2 + (tid >> 7);
        int inner = tid & 127;
        sm[2048 + chunk * 128 + inner] = Bq[chunk * 1024 + nt * 128 + inner];
    }
    __syncthreads();

    int wid = tid >> 6, lane = tid & 63;
    int r = lane & 15, q = lane >> 4;
    int mw = (wid & 1) * 64, nw = (wid >> 1) * 64;
    f32x4 acc[4][4] = {};
#pragma unroll
    for (int ki = 0; ki < 4; ++ki) {
        bf16x8 af[4], bfr[4];
#pragma unroll
        for (int x = 0; x < 4; ++x) {
            af[x] = __builtin_bit_cast(bf16x8,
                                       sm[(ki * 4 + q) * 128 + mw + x * 16 + r]);
            bfr[x] = __builtin_bit_cast(
                bf16x8, sm[2048 + (ki * 4 + q) * 128 + nw + x * 16 + r]);
        }
#pragma unroll
        for (int x = 0; x < 4; ++x)
#pragma unroll
            for (int y = 0; y < 4; ++y)
                acc[x][y] = __builtin_amdgcn_mfma_f32_16x16x32_bf16(
                    af[x], bfr[y], acc[x][y], 0, 0, 0);
    }
    __syncthreads();

    // C frags (col=lane&15, row=q*4+reg) -> LDS f16 tile, then coalesced store.
    _Float16* ct = (_Float16*)sm;
#pragma unroll
    for (int x = 0; x < 4; ++x)
#pragma unroll
        for (int y = 0; y < 4; ++y)
#pragma unroll
            for (int g2 = 0; g2 < 4; ++g2) {
                int row = mw + x * 16 + q * 4 + g2;
                int colc = nw + y * 16 + r;
                ct[row * 128 + colc] = (_Float16)acc[x][y][g2];
            }
    __syncthreads();
    int m = tid >> 1, half = tid & 1;
    const uint4* src = (const uint4*)sm;
    uint4* dstg =
        (uint4*)(Cg + ((size_t)(mt * 128 + m) * NC + nt * 128 + half * 64));
#pragma unroll
    for (int i = 0; i < 8; ++i) dstg[i] = src[m * 16 + half * 8 + i];
}

// ---------------- Recurrent kernel: 64 WGs (1/sample) x 1024 threads.
// Wave w covers columns j = w*16..w*16+15; lane = g*16 + (j&15) owns gate g
// of column j (64 dot4/lane, 16 uint4 weights in VGPRs). Gate exchange via
// __shfl within the wave; ONE __syncthreads per step for the h double buffer.
__global__ __launch_bounds__(1024, 4) void lstm_rec(
    const unsigned short* __restrict__ gx, const uint4* __restrict__ wq4,
    const float* __restrict__ sws, const float* __restrict__ bias,
    float* __restrict__ out) {
    int b = blockIdx.x, tid = threadIdx.x;
    int w = tid >> 6;          // wave 0..15
    int lane = tid & 63;
    int g = lane >> 4;         // gate 0..3 (i,f,g,o)
    int jj = lane & 15;
    int j = w * 16 + jj;       // H column 0..255
    int col = g * H_ + j;      // gate column 0..1023

    // 16 uint4 = 64 dwords of int8 weights for this (g,j), register-resident.
    uint4 wv[16];
#pragma unroll
    for (int i = 0; i < 16; ++i) wv[i] = wq4[col * 16 + i];
    float sc = sws[col];
    float bb = bias[col];

    __shared__ uint4 hq[2][16];  // 256 int8 h values, double buffered
    if (tid < 16) hq[0][tid] = (uint4){0u, 0u, 0u, 0u};
    __syncthreads();

    float c = 0.f;               // live only in owner lanes (g==0)
    const _Float16* gxh = (const _Float16*)gx;
    size_t rowbase = (size_t)b * T_;
    float gxv = (float)gxh[rowbase * NC + col];

    for (int t = 0; t < T_; ++t) {
        size_t row = rowbase + t;
        // prefetch next step's g_x (clamped at the last step; value unused)
        size_t prow = rowbase + ((t < T_ - 1) ? (t + 1) : t);
        float nxv = (float)gxh[prow * NC + col];

        // h broadcast: uniform-address ds_read_b128 (LDS broadcast).
        const uint4* hb = hq[t & 1];
        int a0 = 0, a1 = 0, a2 = 0, a3 = 0;  // 4 chains x 16 deep
#pragma unroll
        for (int ib = 0; ib < 4; ++ib) {
            uint4 h0 = hb[ib * 4 + 0], h1 = hb[ib * 4 + 1];
            uint4 h2 = hb[ib * 4 + 2], h3 = hb[ib * 4 + 3];
            uint4 w0 = wv[ib * 4 + 0], w1 = wv[ib * 4 + 1];
            uint4 w2 = wv[ib * 4 + 2], w3 = wv[ib * 4 + 3];
            a0 = dot4(w0.x, h0.x, a0); a0 = dot4(w0.y, h0.y, a0);
            a0 = dot4(w0.z, h0.z, a0); a0 = dot4(w0.w, h0.w, a0);
            a1 = dot4(w1.x, h1.x, a1); a1 = dot4(w1.y, h1.y, a1);
            a1 = dot4(w1.z, h1.z, a1); a1 = dot4(w1.w, h1.w, a1);
            a2 = dot4(w2.x, h2.x, a2); a2 = dot4(w2.y, h2.y, a2);
            a2 = dot4(w2.z, h2.z, a2); a2 = dot4(w2.w, h2.w, a2);
            a3 = dot4(w3.x, h3.x, a3); a3 = dot4(w3.y, h3.y, a3);
            a3 = dot4(w3.z, h3.z, a3); a3 = dot4(w3.w, h3.w, a3);
        }
        float gpre = (float)((a0 + a1) + (a2 + a3)) * sc + gxv + bb;

        // unified activation: sigmoid for g in {0,1,3}, tanh for g==2
        bool isg = (g == 2);
        float arg = isg ? (-2.f * gpre) : (-gpre);
        float e = __expf(arg);
        float r = fastrcp(1.f + e);
        float v = isg ? (2.f * r - 1.f) : r;

        // in-wave gate exchange (no barrier): owner lanes (g==0) gather f,g,o
        float fv = __shfl(v, jj + 16, 64);
        float gv = __shfl(v, jj + 32, 64);
        float ov = __shfl(v, jj + 48, 64);

        if (g == 0) {  // owner lanes: c/h state for column j
            c = fv * c + v * gv;
            float ec = __expf(-2.f * c);
            float th = 2.f * fastrcp(1.f + ec) - 1.f;  // tanh(c), inf-safe
            float h = ov * th;
            out[row * H_ + j] = h;
            int qv = (int)rintf(h * 127.f);
            ((signed char*)hq[(t + 1) & 1])[j] = (signed char)qv;
        }
        __syncthreads();  // h buffer (t+1) complete before next step reads

        gxv = nxv;
    }
}

extern "C" void kernel_launch(void* const* d_in, const int* in_sizes, int n_in,
                              void* d_out, int out_size, void* d_ws,
                              size_t ws_size, hipStream_t stream) {
    const float* inputs = (const float*)d_in[0];
    const float* Wx = (const float*)d_in[1];
    const float* Wh = (const float*)d_in[2];
    const float* bias = (const float*)d_in[3];
    float* out = (float*)d_out;

    char* ws = (char*)d_ws;
    unsigned short* gxbuf = (unsigned short*)ws;   // 131072*1024 f16 = 256 MiB
    size_t off = (size_t)B_ * T_ * NC * 2;
    unsigned* wq = (unsigned*)(ws + off);          // 256 KiB int8 W_h
    off += (size_t)NC * 64 * 4;
    float* sws = (float*)(ws + off);               // 4 KiB scales
    off += (size_t)NC * 4;
    unsigned short* bxp = (unsigned short*)(ws + off);  // 256 KiB bf16 W_x
    off += (size_t)I_ * NC * 2;

    pack_wh<<<NC, 64, 0, stream>>>(Wh, wq, sws);
    pack_wx<<<(I_ * NC) / 256, 256, 0, stream>>>(Wx, bxp);
    gemm_gx<<<dim3((B_ * T_) / 128, NC / 128), 256, 0, stream>>>(inputs, bxp,
                                                                 gxbuf);
    lstm_rec<<<B_, 1024, 0, stream>>>(gxbuf, (const uint4*)wq, sws, bias, out);
}